// Round 8
// baseline (2069.489 us; speedup 1.0000x reference)
//
#include <hip/hip_runtime.h>
#include <hip/hip_bf16.h>
#include <hip/hip_fp16.h>

#define B_SZ 64
#define T_SZ 2048
#define I_SZ 128
#define H_SZ 256
#define O_SZ 128
#define CH   16   // chains per scan workgroup

typedef _Float16 half_t;
typedef _Float16 h2_t __attribute__((ext_vector_type(2)));
typedef __fp16   fp16x2_t __attribute__((ext_vector_type(2)));
typedef _Float16 h8_t __attribute__((ext_vector_type(8)));
typedef float    f4_t __attribute__((ext_vector_type(4)));
typedef unsigned int u2_t __attribute__((ext_vector_type(2)));

static __device__ __forceinline__ h2_t uint_as_h2(unsigned u) {
  union { unsigned u; h2_t h; } x; x.u = u; return x.h;
}
static __device__ __forceinline__ unsigned pack_h2(float a, float b) {
#if __has_builtin(__builtin_amdgcn_cvt_pkrtz)
  union { fp16x2_t h; unsigned u; } x;
  x.h = __builtin_amdgcn_cvt_pkrtz(a, b);  // one v_cvt_pkrtz_f16_f32
  return x.u;
#else
  h2_t h; h[0] = (_Float16)a; h[1] = (_Float16)b;
  union { h2_t h; unsigned u; } x2; x2.h = h; return x2.u;
#endif
}
static __device__ __forceinline__ float fast_rcp(float x) {
#if __has_builtin(__builtin_amdgcn_rcpf)
  return __builtin_amdgcn_rcpf(x);
#else
  return 1.0f / x;
#endif
}
static __device__ __forceinline__ float tanh_fast(float z) {
  // tanh(z) = 1 - 2/(exp(2z)+1), saturates correctly at +/-inf
  float ex = __expf(2.0f * z);
  return 1.0f - 2.0f * fast_rcp(ex + 1.0f);
}

// ---------------------------------------------------------------------------
// TN GEMM with bias:  C[m,n] = sum_k A[m,k] * Bw[n,k] + bias[n]
// ---------------------------------------------------------------------------
template <int BM, int BN, int BK, int KTOT, bool A_HALF, bool OUT_HALF>
__global__ __launch_bounds__(256, 2) void gemm_tn_bias(
    const void* __restrict__ Ap, const float* __restrict__ Bw,
    const float* __restrict__ bias, void* __restrict__ Out, int ldo) {
  extern __shared__ half_t lds[];
  half_t* As = lds;                 // [BM][BK] swizzled
  half_t* Bs = lds + BM * BK;       // [BN][BK] swizzled

  const int tid = threadIdx.x;
  const long row0 = (long)blockIdx.x * BM;
  const int col0 = blockIdx.y * BN;

  constexpr int MI = 4;
  constexpr int NJ = (BN / 2) / 16;
  const int lane = tid & 63, wid = tid >> 6;
  const int wm = (wid >> 1) * 64;
  const int wn = (wid & 1) * (BN / 2);

  f4_t acc[MI][NJ];
#pragma unroll
  for (int mi = 0; mi < MI; ++mi)
#pragma unroll
    for (int nj = 0; nj < NJ; ++nj) acc[mi][nj] = (f4_t){0.f, 0.f, 0.f, 0.f};

#pragma unroll 1
  for (int kt = 0; kt < KTOT / BK; ++kt) {
    if (kt) __syncthreads();
    constexpr int AIT = (BM * BK) / (256 * 8);
#pragma unroll
    for (int it = 0; it < AIT; ++it) {
      int idx = (it * 256 + tid) * 8;
      int r = idx / BK, c = idx % BK;
      uint4 v;
      if (A_HALF) {
        v = *(const uint4*)((const half_t*)Ap + (row0 + r) * (long)KTOT +
                            kt * BK + c);
      } else {
        const float* src =
            (const float*)Ap + (row0 + r) * (long)KTOT + kt * BK + c;
        float4 f0 = *(const float4*)(src);
        float4 f1 = *(const float4*)(src + 4);
        v.x = pack_h2(f0.x, f0.y); v.y = pack_h2(f0.z, f0.w);
        v.z = pack_h2(f1.x, f1.y); v.w = pack_h2(f1.z, f1.w);
      }
      int chunk = (c >> 3) ^ (r & 7);
      *(uint4*)(&As[r * BK + chunk * 8]) = v;
    }
    constexpr int BIT = (BN * BK) / (256 * 8);
#pragma unroll
    for (int it = 0; it < BIT; ++it) {
      int idx = (it * 256 + tid) * 8;
      int r = idx / BK, c = idx % BK;
      const float* src = Bw + (long)(col0 + r) * KTOT + kt * BK + c;
      float4 f0 = *(const float4*)(src);
      float4 f1 = *(const float4*)(src + 4);
      uint4 v;
      v.x = pack_h2(f0.x, f0.y); v.y = pack_h2(f0.z, f0.w);
      v.z = pack_h2(f1.x, f1.y); v.w = pack_h2(f1.z, f1.w);
      int chunk = (c >> 3) ^ (r & 7);
      *(uint4*)(&Bs[r * BK + chunk * 8]) = v;
    }
    __syncthreads();

#pragma unroll
    for (int ks = 0; ks < BK / 32; ++ks) {
      h8_t af[MI], bf[NJ];
#pragma unroll
      for (int mi = 0; mi < MI; ++mi) {
        int r = wm + mi * 16 + (lane & 15);
        int chunk = (ks * 4 + (lane >> 4)) ^ (r & 7);
        af[mi] = *(const h8_t*)(&As[r * BK + chunk * 8]);
      }
#pragma unroll
      for (int nj = 0; nj < NJ; ++nj) {
        int r = wn + nj * 16 + (lane & 15);
        int chunk = (ks * 4 + (lane >> 4)) ^ (r & 7);
        bf[nj] = *(const h8_t*)(&Bs[r * BK + chunk * 8]);
      }
#pragma unroll
      for (int mi = 0; mi < MI; ++mi)
#pragma unroll
        for (int nj = 0; nj < NJ; ++nj)
          acc[mi][nj] = __builtin_amdgcn_mfma_f32_16x16x32_f16(
              af[mi], bf[nj], acc[mi][nj], 0, 0, 0);
    }
  }

#pragma unroll
  for (int mi = 0; mi < MI; ++mi) {
#pragma unroll
    for (int nj = 0; nj < NJ; ++nj) {
#pragma unroll
      for (int e = 0; e < 4; ++e) {
        long row = row0 + wm + mi * 16 + (lane >> 4) * 4 + e;
        int col = col0 + wn + nj * 16 + (lane & 15);
        float val = acc[mi][nj][e] + bias[col];
        if (OUT_HALF)
          ((half_t*)Out)[row * ldo + col] = (half_t)val;
        else
          ((float*)Out)[row * ldo + col] = val;
      }
    }
  }
}

// ---------------------------------------------------------------------------
// MFMA recurrent scan: 4 WGs x 16 chains. 512 thr = 8 waves; wave w owns
// neuron tiles {2w, 2w+1} (neurons [32w, 32w+32)).
// Per step: preact[neuron, chain] = sum_k Whh[neuron,k] * h[chain,k] via
// mfma_f32_16x16x32_f16 accumulating over 8 K-slices (the K-reduction lives
// in the MFMA accumulator -> no cross-lane shuffle on the critical path).
// Whh A-fragments stay in VGPRs for all T steps. h in 16KB double-buffered
// LDS, XOR-swizzled (^ (chain&7)<<4) -> writes conflict-free, reads
// uniformly bank-spread. One barrier per step (double buffer).
// D-fragment: col = lane&15 = chain, row = (lane>>4)*4+e = neuron-in-tile.
// ---------------------------------------------------------------------------
__global__ __launch_bounds__(512, 1) void rnn_scan_mfma(
    const half_t* __restrict__ Xp,   // (B*T, H) f16 (aliases d_out)
    const float* __restrict__ Whh,   // (H, H) fp32
    const float* __restrict__ h0,    // (B, H) fp32
    half_t* __restrict__ Hs,         // (B*T, H) f16 (ws)
    float* __restrict__ hT) {        // (B, H) fp32 (d_out tail)
  __shared__ __align__(16) unsigned char hl[2][CH * 512];
  const int tid = threadIdx.x;
  const int b0 = blockIdx.x * CH;
  const int lane = tid & 63;
  const int w = tid >> 6;
  const int chain = lane & 15;
  const int hi = lane >> 4;
  const int swz = (chain & 7) << 4;

  // --- Whh A-fragments: 2 m-tiles x 8 K-slices, fp32 -> packed f16 ---
  h8_t wfrag[2][8];
#pragma unroll
  for (int mt2 = 0; mt2 < 2; ++mt2) {
    const int row = (2 * w + mt2) * 16 + chain;
#pragma unroll
    for (int ks = 0; ks < 8; ++ks) {
      const float* p = Whh + row * H_SZ + ks * 32 + hi * 8;
      float4 f0 = *(const float4*)(p);
      float4 f1 = *(const float4*)(p + 4);
      union { unsigned u[4]; h8_t h; } cv;
      cv.u[0] = pack_h2(f0.x, f0.y); cv.u[1] = pack_h2(f0.z, f0.w);
      cv.u[2] = pack_h2(f1.x, f1.y); cv.u[3] = pack_h2(f1.z, f1.w);
      wfrag[mt2][ks] = cv.h;
    }
  }
  // --- h0 into buffer 0 (f16, swizzled) ---
  {
    const int c = tid >> 5;           // chain
    const int col = (tid & 31) * 8;   // neuron start
    const float* p = h0 + (long)(b0 + c) * H_SZ + col;
    float4 f0 = *(const float4*)(p);
    float4 f1 = *(const float4*)(p + 4);
    uint4 v;
    v.x = pack_h2(f0.x, f0.y); v.y = pack_h2(f0.z, f0.w);
    v.z = pack_h2(f1.x, f1.y); v.w = pack_h2(f1.z, f1.w);
    *(uint4*)&hl[0][(c * 512 + col * 2) ^ ((c & 7) << 4)] = v;
  }
  __syncthreads();

  const int n0[2] = {(2 * w) * 16 + hi * 4, (2 * w + 1) * 16 + hi * 4};
  const half_t* xb = Xp + (long)(b0 + chain) * T_SZ * H_SZ;
  half_t* hsb = Hs + (long)(b0 + chain) * T_SZ * H_SZ;
  float* hTb = hT + (long)(b0 + chain) * H_SZ;

  u2_t xcur[4][2], xnxt[4][2];
#pragma unroll
  for (int j = 0; j < 4; ++j) {
    xcur[j][0] = *(const u2_t*)(xb + (long)j * H_SZ + n0[0]);
    xcur[j][1] = *(const u2_t*)(xb + (long)j * H_SZ + n0[1]);
  }

#pragma unroll 1
  for (int tc = 0; tc < T_SZ; tc += 4) {
    // prefetch next 4 steps' x (clamped; consumed one group later)
#pragma unroll
    for (int j = 0; j < 4; ++j) {
      long tt = tc + 4 + j;
      if (tt > T_SZ - 1) tt = T_SZ - 1;
      xnxt[j][0] = *(const u2_t*)(xb + tt * H_SZ + n0[0]);
      xnxt[j][1] = *(const u2_t*)(xb + tt * H_SZ + n0[1]);
    }
#pragma unroll
    for (int j = 0; j < 4; ++j) {
      const int t = tc + j;
      const int cur = t & 1;
      // B-fragments of h (shared across both m-tiles)
      h8_t hf[8];
#pragma unroll
      for (int ks = 0; ks < 8; ++ks)
        hf[ks] =
            *(const h8_t*)&hl[cur][(chain * 512 + ks * 64 + hi * 16) ^ swz];
      // 2 partial accumulators per m-tile -> 4-deep dependent MFMA chains
      f4_t a0[2], a1[2];
#pragma unroll
      for (int mt2 = 0; mt2 < 2; ++mt2) {
        a0[mt2] = (f4_t){0.f, 0.f, 0.f, 0.f};
        a1[mt2] = (f4_t){0.f, 0.f, 0.f, 0.f};
#pragma unroll
        for (int ks = 0; ks < 8; ks += 2) {
          a0[mt2] = __builtin_amdgcn_mfma_f32_16x16x32_f16(
              wfrag[mt2][ks], hf[ks], a0[mt2], 0, 0, 0);
          a1[mt2] = __builtin_amdgcn_mfma_f32_16x16x32_f16(
              wfrag[mt2][ks + 1], hf[ks + 1], a1[mt2], 0, 0, 0);
        }
      }
#pragma unroll
      for (int mt2 = 0; mt2 < 2; ++mt2) {
        f4_t acc = a0[mt2] + a1[mt2];
        h2_t xlo = uint_as_h2(xcur[j][mt2][0]);
        h2_t xhi = uint_as_h2(xcur[j][mt2][1]);
        float v0 = tanh_fast(acc[0] + (float)xlo[0]);
        float v1 = tanh_fast(acc[1] + (float)xlo[1]);
        float v2 = tanh_fast(acc[2] + (float)xhi[0]);
        float v3 = tanh_fast(acc[3] + (float)xhi[1]);
        u2_t pk;
        pk[0] = pack_h2(v0, v1);
        pk[1] = pack_h2(v2, v3);
        // next-step h (double buffer, swizzled)
        const int woff =
            (chain * 512 + ((2 * w + mt2) * 16 + hi * 4) * 2) ^ swz;
        *(u2_t*)&hl[cur ^ 1][woff] = pk;
        // stream h_t out for Phase C
        *(u2_t*)(hsb + (long)t * H_SZ + n0[mt2]) = pk;
        if (t == T_SZ - 1) {
          float4 fo = {v0, v1, v2, v3};
          *(float4*)(hTb + n0[mt2]) = fo;
        }
      }
      __syncthreads();
    }
#pragma unroll
    for (int j = 0; j < 4; ++j) {
      xcur[j][0] = xnxt[j][0];
      xcur[j][1] = xnxt[j][1];
    }
  }
}

extern "C" void kernel_launch(void* const* d_in, const int* in_sizes, int n_in,
                              void* d_out, int out_size, void* d_ws,
                              size_t ws_size, hipStream_t stream) {
  const float* x = (const float*)d_in[0];
  const float* h0 = (const float*)d_in[1];
  const float* Wxh = (const float*)d_in[2];
  const float* Whh = (const float*)d_in[3];
  const float* bh = (const float*)d_in[4];
  const float* Wout = (const float*)d_in[5];
  const float* bout = (const float*)d_in[6];

  // d_out: [0, 64MB) first holds f16 Xp scratch, finally Y fp32;
  // hT tail at element offset B*T*O is beyond the Xp region.
  half_t* Xp = (half_t*)d_out;
  half_t* Hs = (half_t*)d_ws;  // 64 MB
  float* Y = (float*)d_out;
  float* hT = (float*)d_out + (long)B_SZ * T_SZ * O_SZ;

  const long M = (long)B_SZ * T_SZ;  // 131072

  // Phase A: Xp = f16(x @ Wxh^T + bh)   M x 256, K=128
  {
    dim3 grid((unsigned)(M / 128), H_SZ / 128);
    size_t sh = 2ull * 128 * 128 * sizeof(half_t);  // 64 KB
    hipLaunchKernelGGL((gemm_tn_bias<128, 128, 128, 128, false, true>), grid,
                       dim3(256), sh, stream, (const void*)x, Wxh, bh,
                       (void*)Xp, H_SZ);
  }
  // Phase B: MFMA scan, 4 WGs x 16 chains
  hipLaunchKernelGGL(rnn_scan_mfma, dim3(B_SZ / CH), dim3(512), 0, stream, Xp,
                     Whh, h0, Hs, hT);
  // Phase C: Y = Hs @ Wout^T + bout   M x 128, K=256
  {
    dim3 grid((unsigned)(M / 128), O_SZ / 128);
    size_t sh = 2ull * 128 * 128 * sizeof(half_t);  // 64 KB
    hipLaunchKernelGGL((gemm_tn_bias<128, 128, 128, 256, true, false>), grid,
                       dim3(256), sh, stream, (const void*)Hs, Wout, bout,
                       (void*)Y, O_SZ);
  }
}